// Round 2
// baseline (3493.125 us; speedup 1.0000x reference)
//
#include <hip/hip_runtime.h>
#include <hip/hip_bf16.h>
#include <stdint.h>

#define T_NUM 1024
#define H_DIM 2048
#define E_NUM 16
#define TOPK 4
#define I_DIM 1408
#define SHI_DIM 2816

typedef __attribute__((ext_vector_type(4))) float f32x4;
typedef __attribute__((ext_vector_type(8))) short bf16x8;
typedef __attribute__((ext_vector_type(4))) short s16x4;

static __device__ __forceinline__ short f2bf(float f) {
    __hip_bfloat16 h = __float2bfloat16(f);
    return __builtin_bit_cast(short, h);
}

// ---------------- router: fp32 logits -> softmax -> top4 ----------------
__global__ void router_kernel(const float* __restrict__ x, const float* __restrict__ wgate,
                              int* __restrict__ top_e, float* __restrict__ top_w) {
    const int t = blockIdx.x;
    const int tid = threadIdx.x;       // 256 threads
    __shared__ float xsh[H_DIM];
    const float* xr = x + (size_t)t * H_DIM;
    for (int h = tid; h < H_DIM; h += 256) xsh[h] = xr[h];
    __syncthreads();

    const int e = tid >> 4;            // 0..15
    const int j = tid & 15;
    const float* wr = wgate + (size_t)e * H_DIM;
    float acc = 0.f;
    for (int h = j; h < H_DIM; h += 16) acc += xsh[h] * wr[h];
    #pragma unroll
    for (int m = 8; m >= 1; m >>= 1) acc += __shfl_down(acc, m, 16);

    __shared__ float logits[E_NUM];
    if (j == 0) logits[e] = acc;
    __syncthreads();

    if (tid == 0) {
        float mx = logits[0];
        #pragma unroll
        for (int i = 1; i < E_NUM; ++i) mx = fmaxf(mx, logits[i]);
        float p[E_NUM]; float s = 0.f;
        #pragma unroll
        for (int i = 0; i < E_NUM; ++i) { p[i] = expf(logits[i] - mx); s += p[i]; }
        const float inv = 1.f / s;
        #pragma unroll
        for (int i = 0; i < E_NUM; ++i) p[i] *= inv;
        for (int k = 0; k < TOPK; ++k) {
            float best = -1.f; int bi = 0;
            #pragma unroll
            for (int i = 0; i < E_NUM; ++i) if (p[i] > best) { best = p[i]; bi = i; }
            top_e[t * TOPK + k] = bi;
            top_w[t * TOPK + k] = best;
            p[bi] = -2.f;
        }
    }
}

// ------- stable bucket sort of 4096 slots by expert (deterministic) -------
__global__ void perm_kernel(const int* __restrict__ top_e,
                            int* __restrict__ offs, int* __restrict__ perm) {
    __shared__ int cnt[256][E_NUM];
    __shared__ int base[E_NUM];
    const int tid = threadIdx.x;
    int c[E_NUM];
    #pragma unroll
    for (int i = 0; i < E_NUM; ++i) c[i] = 0;
    for (int s = tid * 16; s < tid * 16 + 16; ++s) c[top_e[s]]++;
    #pragma unroll
    for (int i = 0; i < E_NUM; ++i) cnt[tid][i] = c[i];
    __syncthreads();
    if (tid < E_NUM) {
        int run = 0;
        for (int b = 0; b < 256; ++b) { int v = cnt[b][tid]; cnt[b][tid] = run; run += v; }
        base[tid] = run;               // per-expert total
    }
    __syncthreads();
    if (tid == 0) {
        int run = 0;
        for (int e2 = 0; e2 < E_NUM; ++e2) { int v = base[e2]; base[e2] = run; offs[e2] = run; run += v; }
        offs[E_NUM] = run;             // = 4096
    }
    __syncthreads();
    int run[E_NUM];
    #pragma unroll
    for (int i = 0; i < E_NUM; ++i) run[i] = base[i] + cnt[tid][i];
    for (int s = tid * 16; s < tid * 16 + 16; ++s) {
        int e2 = top_e[s];
        perm[run[e2]++] = s;
    }
}

// ---------------- GEMM template ----------------
// MODE 0: routed SwiGLU  : A=x(f32) gathered, B=wg[e],wu[e], out=act_r bf16 [slot]
// MODE 1: shared SwiGLU  : A=x(f32) dense,    B=sg,su,       out=act_s bf16 [row]
// MODE 2: routed down    : A=act_r(bf16) gathered, B=wd[e],  out=atomicAdd f32 out[token]
// MODE 3: shared down    : A=act_s(bf16) dense,    B=sd,     out=store f32 out[row]
template<int MODE>
__global__ __launch_bounds__(256, 4) void moe_gemm(
    const void* __restrict__ Av, int lda, int Kdim,
    const float* __restrict__ B1g, const float* __restrict__ B2g, int ldb,
    void* __restrict__ Outv, int ldo,
    const int* __restrict__ perm, const int* __restrict__ offs,
    const float* __restrict__ top_w,
    int nmt, int nnt)
{
    constexpr bool ABF = (MODE == 2 || MODE == 3);     // A is bf16
    constexpr int NB = (MODE == 0 || MODE == 1) ? 2 : 1;
    constexpr int BM = 128, BN = 128, BK = 32, KP = 40;
    __shared__ short As[BM * KP];                      // single buffer (reg-prefetch)
    __shared__ short Bs[NB * BN * KP];
    __shared__ int   rows_a[BM];
    __shared__ int   rows_o[BM];
    __shared__ float w_m[BM];

    const int tid = threadIdx.x;

    // bijective XCD swizzle (m204): consecutive logical ids land on one XCD,
    // and mt is innermost so blocks sharing a B-strip share that XCD's L2.
    int wg = blockIdx.x;
    {
        const int nwg = gridDim.x;
        const int qq = nwg >> 3, rr = nwg & 7;
        const int xcd = wg & 7, lin = wg >> 3;
        wg = (xcd < rr ? xcd * (qq + 1) : rr * (qq + 1) + (xcd - rr) * qq) + lin;
    }
    const int mt = wg % nmt;
    const int nt = (wg / nmt) % nnt;
    const int e  = wg / (nmt * nnt);

    int off = 0, cnt = T_NUM;
    const float* B1 = B1g;
    const float* B2 = B2g;
    if constexpr (MODE == 0) {
        off = offs[e]; cnt = offs[e + 1] - off;
        if (mt * BM >= cnt) return;
        B1 = B1g + (size_t)e * H_DIM * I_DIM;
        B2 = B2g + (size_t)e * H_DIM * I_DIM;
    }
    if constexpr (MODE == 2) {
        off = offs[e]; cnt = offs[e + 1] - off;
        if (mt * BM >= cnt) return;
        B1 = B1g + (size_t)e * I_DIM * H_DIM;
    }

    if (tid < BM) {
        const int gm = mt * BM + tid;
        if constexpr (MODE == 0) {
            int s = perm[off + (gm < cnt ? gm : cnt - 1)];
            rows_a[tid] = s >> 2; rows_o[tid] = s; w_m[tid] = 1.f;
        } else if constexpr (MODE == 2) {
            int s = perm[off + (gm < cnt ? gm : cnt - 1)];
            rows_a[tid] = s; rows_o[tid] = s >> 2; w_m[tid] = top_w[s];
        } else {
            rows_a[tid] = gm; rows_o[tid] = gm; w_m[tid] = 1.f;
        }
    }
    __syncthreads();

    // staging registers
    f32x4  aRegF[4];     // fp32-A path
    bf16x8 aRegH[2];     // bf16-A path
    float  bReg[NB][4][4];

    auto gload = [&](int kt) {
        const int k0 = kt * BK;
        if constexpr (!ABF) {
            const float* A = (const float*)Av;
            #pragma unroll
            for (int it = 0; it < 4; ++it) {
                const int q = it * 256 + tid;
                const int m = q >> 3, kq = (q & 7) * 4;
                aRegF[it] = *reinterpret_cast<const f32x4*>(A + (size_t)rows_a[m] * lda + k0 + kq);
            }
        } else {
            const short* A = (const short*)Av;
            #pragma unroll
            for (int it = 0; it < 2; ++it) {
                const int q = it * 256 + tid;
                const int m = q >> 2, ko = (q & 3) * 8;
                aRegH[it] = *reinterpret_cast<const bf16x8*>(A + (size_t)rows_a[m] * lda + k0 + ko);
            }
        }
        #pragma unroll
        for (int it = 0; it < 4; ++it) {
            const int q = it * 256 + tid;
            const int n = q & 127, kb = (q >> 7) * 4;
            const float* p1 = B1 + (size_t)(k0 + kb) * ldb + (size_t)nt * BN + n;
            #pragma unroll
            for (int dk = 0; dk < 4; ++dk) bReg[0][it][dk] = p1[(size_t)dk * ldb];
            if constexpr (NB == 2) {
                const float* p2 = B2 + (size_t)(k0 + kb) * ldb + (size_t)nt * BN + n;
                #pragma unroll
                for (int dk = 0; dk < 4; ++dk) bReg[1][it][dk] = p2[(size_t)dk * ldb];
            }
        }
    };

    auto swrite = [&]() {
        if constexpr (!ABF) {
            #pragma unroll
            for (int it = 0; it < 4; ++it) {
                const int q = it * 256 + tid;
                const int m = q >> 3, kq = (q & 7) * 4;
                s16x4 v = { f2bf(aRegF[it][0]), f2bf(aRegF[it][1]), f2bf(aRegF[it][2]), f2bf(aRegF[it][3]) };
                *reinterpret_cast<s16x4*>(&As[m * KP + kq]) = v;
            }
        } else {
            #pragma unroll
            for (int it = 0; it < 2; ++it) {
                const int q = it * 256 + tid;
                const int m = q >> 2, ko = (q & 3) * 8;
                *reinterpret_cast<bf16x8*>(&As[m * KP + ko]) = aRegH[it];
            }
        }
        #pragma unroll
        for (int it = 0; it < 4; ++it) {
            const int q = it * 256 + tid;
            const int n = q & 127, kb = (q >> 7) * 4;
            #pragma unroll
            for (int mat = 0; mat < NB; ++mat) {
                s16x4 v = { f2bf(bReg[mat][it][0]), f2bf(bReg[mat][it][1]),
                            f2bf(bReg[mat][it][2]), f2bf(bReg[mat][it][3]) };
                *reinterpret_cast<s16x4*>(&Bs[mat * BN * KP + n * KP + kb]) = v;
            }
        }
    };

    f32x4 acc1[4][4], acc2[4][4];
    #pragma unroll
    for (int i = 0; i < 4; ++i)
        #pragma unroll
        for (int j = 0; j < 4; ++j) { acc1[i][j] = (f32x4)0.f; acc2[i][j] = (f32x4)0.f; }

    const int lane = tid & 63;
    const int wr = (tid >> 6) >> 1, wc = (tid >> 6) & 1;
    const int lrow = lane & 15;
    const int lko = (lane >> 4) * 8;

    auto compute = [&]() {
        bf16x8 af[4];
        #pragma unroll
        for (int mi = 0; mi < 4; ++mi)
            af[mi] = *reinterpret_cast<const bf16x8*>(&As[(wr * 64 + mi * 16 + lrow) * KP + lko]);
        #pragma unroll
        for (int ni = 0; ni < 4; ++ni) {
            const int brow = (wc * 64 + ni * 16 + lrow) * KP + lko;
            bf16x8 b1 = *reinterpret_cast<const bf16x8*>(&Bs[brow]);
            #pragma unroll
            for (int mi = 0; mi < 4; ++mi)
                acc1[mi][ni] = __builtin_amdgcn_mfma_f32_16x16x32_bf16(af[mi], b1, acc1[mi][ni], 0, 0, 0);
            if constexpr (NB == 2) {
                bf16x8 b2 = *reinterpret_cast<const bf16x8*>(&Bs[BN * KP + brow]);
                #pragma unroll
                for (int mi = 0; mi < 4; ++mi)
                    acc2[mi][ni] = __builtin_amdgcn_mfma_f32_16x16x32_bf16(af[mi], b2, acc2[mi][ni], 0, 0, 0);
            }
        }
    };

    const int NK = Kdim / BK;
    gload(0);
    for (int kt = 0; kt < NK; ++kt) {
        __syncthreads();                 // prior compute finished reading LDS
        swrite();                        // drains in-flight gloads (vmcnt)
        __syncthreads();
        if (kt + 1 < NK) gload(kt + 1);  // issue next tile; overlaps compute
        compute();
    }

    // epilogue
    #pragma unroll
    for (int mi = 0; mi < 4; ++mi) {
        #pragma unroll
        for (int j = 0; j < 4; ++j) {
            const int ml = wr * 64 + mi * 16 + (lane >> 4) * 4 + j;
            const int gm = mt * BM + ml;
            if constexpr (MODE == 0 || MODE == 2) { if (gm >= cnt) continue; }
            const int orow = rows_o[ml];
            const float wsc = w_m[ml];
            #pragma unroll
            for (int ni = 0; ni < 4; ++ni) {
                const int n = nt * BN + wc * 64 + ni * 16 + (lane & 15);
                const float v1 = acc1[mi][ni][j];
                if constexpr (NB == 2) {
                    const float u = acc2[mi][ni][j];
                    const float s = v1 / (1.f + __expf(-v1));   // silu(g)
                    ((__hip_bfloat16*)Outv)[(size_t)orow * ldo + n] = __float2bfloat16(s * u);
                } else if constexpr (MODE == 2) {
                    atomicAdd(&((float*)Outv)[(size_t)orow * ldo + n], v1 * wsc);
                } else {
                    ((float*)Outv)[(size_t)orow * ldo + n] = v1;
                }
            }
        }
    }
}

extern "C" void kernel_launch(void* const* d_in, const int* in_sizes, int n_in,
                              void* d_out, int out_size, void* d_ws, size_t ws_size,
                              hipStream_t stream) {
    const float* x     = (const float*)d_in[0];
    const float* wgate = (const float*)d_in[1];
    const float* wg    = (const float*)d_in[2];
    const float* wu    = (const float*)d_in[3];
    const float* wd    = (const float*)d_in[4];
    const float* sg    = (const float*)d_in[5];
    const float* su    = (const float*)d_in[6];
    const float* sd    = (const float*)d_in[7];
    float* out = (float*)d_out;

    uintptr_t p = (uintptr_t)d_ws;
    auto alloc = [&](size_t bytes) {
        p = (p + 255) & ~(uintptr_t)255;
        void* r = (void*)p; p += bytes; return r;
    };
    int*   top_e = (int*)alloc((size_t)T_NUM * TOPK * sizeof(int));
    float* top_w = (float*)alloc((size_t)T_NUM * TOPK * sizeof(float));
    int*   offs  = (int*)alloc((E_NUM + 1) * sizeof(int));
    int*   perm  = (int*)alloc((size_t)T_NUM * TOPK * sizeof(int));
    __hip_bfloat16* act_r = (__hip_bfloat16*)alloc((size_t)T_NUM * TOPK * I_DIM * 2);  // 11.5 MB
    __hip_bfloat16* act_s = (__hip_bfloat16*)alloc((size_t)T_NUM * SHI_DIM * 2);       // 5.8 MB

    router_kernel<<<T_NUM, 256, 0, stream>>>(x, wgate, top_e, top_w);
    perm_kernel<<<1, 256, 0, stream>>>(top_e, offs, perm);

    // shared SwiGLU: act_s = silu(x@sg)*(x@su)         grid = 8*22 = 176
    moe_gemm<1><<<(T_NUM / 128) * (SHI_DIM / 128), 256, 0, stream>>>(
        x, H_DIM, H_DIM, sg, su, SHI_DIM, act_s, SHI_DIM, nullptr, nullptr, nullptr,
        T_NUM / 128, SHI_DIM / 128);
    // shared down: out = act_s @ sd (plain stores init out)  grid = 8*16 = 128
    moe_gemm<3><<<(T_NUM / 128) * (H_DIM / 128), 256, 0, stream>>>(
        act_s, SHI_DIM, SHI_DIM, sd, nullptr, H_DIM, out, H_DIM, nullptr, nullptr, nullptr,
        T_NUM / 128, H_DIM / 128);
    // routed SwiGLU per expert (gathered rows of x)     grid = 8*11*16 = 1408
    moe_gemm<0><<<(T_NUM / 128) * (I_DIM / 128) * E_NUM, 256, 0, stream>>>(
        x, H_DIM, H_DIM, wg, wu, I_DIM, act_r, I_DIM, perm, offs, nullptr,
        T_NUM / 128, I_DIM / 128);
    // routed down per expert: out[token] += w * (act_r[slot] @ wd[e])  grid = 8*16*16 = 2048
    moe_gemm<2><<<(T_NUM / 128) * (H_DIM / 128) * E_NUM, 256, 0, stream>>>(
        act_r, I_DIM, I_DIM, wd, nullptr, H_DIM, out, H_DIM, perm, offs, top_w,
        T_NUM / 128, H_DIM / 128);
}

// Round 3
// 631.384 us; speedup vs baseline: 5.5325x; 5.5325x over previous
//
#include <hip/hip_runtime.h>
#include <hip/hip_bf16.h>
#include <stdint.h>

#define T_NUM 1024
#define H_DIM 2048
#define E_NUM 16
#define TOPK 4
#define I_DIM 1408
#define SHI_DIM 2816

typedef __attribute__((ext_vector_type(4))) float f32x4;
typedef __attribute__((ext_vector_type(8))) short bf16x8;
typedef __attribute__((ext_vector_type(4))) short s16x4;

static __device__ __forceinline__ short f2bf(float f) {
    __hip_bfloat16 h = __float2bfloat16(f);
    return __builtin_bit_cast(short, h);
}
static __device__ __forceinline__ float bf2f(short s) {
    return __bfloat162float(__builtin_bit_cast(__hip_bfloat16, s));
}

static __device__ __forceinline__ void gll16(const short* g, const short* l) {
    __builtin_amdgcn_global_load_lds(
        (const __attribute__((address_space(1))) void*)g,
        (__attribute__((address_space(3))) void*)l, 16, 0, 0);
}

// ---------------- router: fp32 logits -> softmax -> top4 (+ x -> bf16) ------
__global__ void router_kernel(const float* __restrict__ x, const float* __restrict__ wgate,
                              int* __restrict__ top_e, float* __restrict__ top_w,
                              short* __restrict__ xb) {
    const int t = blockIdx.x;
    const int tid = threadIdx.x;       // 256 threads
    __shared__ float xsh[H_DIM];
    const float* xr = x + (size_t)t * H_DIM;
    for (int h = tid; h < H_DIM; h += 256) xsh[h] = xr[h];
    __syncthreads();

    // write bf16 copy of x (8 elems/thread)
    {
        short v[8];
        #pragma unroll
        for (int i = 0; i < 8; ++i) v[i] = f2bf(xsh[tid * 8 + i]);
        *reinterpret_cast<bf16x8*>(xb + (size_t)t * H_DIM + tid * 8) = *(bf16x8*)v;
    }

    const int e = tid >> 4;            // 0..15
    const int j = tid & 15;
    const float* wr = wgate + (size_t)e * H_DIM;
    float acc = 0.f;
    for (int h = j; h < H_DIM; h += 16) acc += xsh[h] * wr[h];
    #pragma unroll
    for (int m = 8; m >= 1; m >>= 1) acc += __shfl_down(acc, m, 16);

    __shared__ float logits[E_NUM];
    if (j == 0) logits[e] = acc;
    __syncthreads();

    if (tid == 0) {
        float mx = logits[0];
        #pragma unroll
        for (int i = 1; i < E_NUM; ++i) mx = fmaxf(mx, logits[i]);
        float p[E_NUM]; float s = 0.f;
        #pragma unroll
        for (int i = 0; i < E_NUM; ++i) { p[i] = expf(logits[i] - mx); s += p[i]; }
        const float inv = 1.f / s;
        #pragma unroll
        for (int i = 0; i < E_NUM; ++i) p[i] *= inv;
        for (int k = 0; k < TOPK; ++k) {
            float best = -1.f; int bi = 0;
            #pragma unroll
            for (int i = 0; i < E_NUM; ++i) if (p[i] > best) { best = p[i]; bi = i; }
            top_e[t * TOPK + k] = bi;
            top_w[t * TOPK + k] = best;
            p[bi] = -2.f;
        }
    }
}

// ------- stable bucket sort of 4096 slots by expert (deterministic) -------
__global__ void perm_kernel(const int* __restrict__ top_e,
                            int* __restrict__ offs, int* __restrict__ perm) {
    __shared__ int cnt[256][E_NUM];
    __shared__ int base[E_NUM];
    const int tid = threadIdx.x;
    int c[E_NUM];
    #pragma unroll
    for (int i = 0; i < E_NUM; ++i) c[i] = 0;
    for (int s = tid * 16; s < tid * 16 + 16; ++s) c[top_e[s]]++;
    #pragma unroll
    for (int i = 0; i < E_NUM; ++i) cnt[tid][i] = c[i];
    __syncthreads();
    if (tid < E_NUM) {
        int run = 0;
        for (int b = 0; b < 256; ++b) { int v = cnt[b][tid]; cnt[b][tid] = run; run += v; }
        base[tid] = run;
    }
    __syncthreads();
    if (tid == 0) {
        int run = 0;
        for (int e2 = 0; e2 < E_NUM; ++e2) { int v = base[e2]; base[e2] = run; offs[e2] = run; run += v; }
        offs[E_NUM] = run;
    }
    __syncthreads();
    int run[E_NUM];
    #pragma unroll
    for (int i = 0; i < E_NUM; ++i) run[i] = base[i] + cnt[tid][i];
    for (int s = tid * 16; s < tid * 16 + 16; ++s) {
        int e2 = top_e[s];
        perm[run[e2]++] = s;
    }
}

// ------- transpose+convert: src f32 [mat][R][C] -> dst bf16 [mat][C][R] -------
__global__ void tconv_kernel(const float* __restrict__ src, short* __restrict__ dst,
                             int R, int C) {
    __shared__ float t[64][65];
    const int c0 = blockIdx.x * 64, r0 = blockIdx.y * 64;
    const size_t mo = (size_t)blockIdx.z * R * C;
    const float* s = src + mo;
    short* d = dst + mo;
    const int tid = threadIdx.x;
    #pragma unroll
    for (int it = 0; it < 4; ++it) {
        const int q = it * 256 + tid;
        const int r = q >> 4, c4 = (q & 15) * 4;
        f32x4 v = *reinterpret_cast<const f32x4*>(s + (size_t)(r0 + r) * C + c0 + c4);
        t[r][c4] = v[0]; t[r][c4 + 1] = v[1]; t[r][c4 + 2] = v[2]; t[r][c4 + 3] = v[3];
    }
    __syncthreads();
    #pragma unroll
    for (int it = 0; it < 2; ++it) {
        const int q = it * 256 + tid;
        const int c = q >> 3, r8 = (q & 7) * 8;
        short v[8];
        #pragma unroll
        for (int i = 0; i < 8; ++i) v[i] = f2bf(t[r8 + i][c]);
        *reinterpret_cast<bf16x8*>(d + (size_t)(c0 + c) * R + r0 + r8) = *(bf16x8*)v;
    }
}

// ------- SwiGLU combine: act = silu(g) * u  (bf16 elementwise) -------
__global__ void swiglu_kernel(const short* __restrict__ g, const short* __restrict__ u,
                              short* __restrict__ act, int n8) {
    const int i = blockIdx.x * 256 + threadIdx.x;
    if (i >= n8) return;
    bf16x8 gv = *reinterpret_cast<const bf16x8*>(g + (size_t)i * 8);
    bf16x8 uv = *reinterpret_cast<const bf16x8*>(u + (size_t)i * 8);
    short o[8];
    #pragma unroll
    for (int j = 0; j < 8; ++j) {
        float gf = bf2f(gv[j]);
        float uf = bf2f(uv[j]);
        o[j] = f2bf(gf / (1.f + __expf(-gf)) * uf);
    }
    *reinterpret_cast<bf16x8*>(act + (size_t)i * 8) = *(bf16x8*)o;
}

// ---------------- bf16 GEMM, global_load_lds + 2-phase counted vmcnt ----------
// A: bf16 [rows][K] k-contig.  B: bf16 [mat][N][K] k-contig (pre-transposed).
// MODE 0: routed up/gate  (A=xb gathered by token; out bf16 [slot][N])
// MODE 1: shared up/gate  (A=xb dense;             out bf16 [row][N])
// MODE 2: routed down     (A=act_r gathered;       out f32 atomicAdd [token][N] * w)
// MODE 3: shared down     (A=act_s dense;          out f32 store [row][N])
template<int MODE>
__global__ __launch_bounds__(256, 4) void gemm_bf(
    const short* __restrict__ A, int lda, int Kdim,
    const short* __restrict__ Bg,
    void* __restrict__ Outv, int ldo,
    const int* __restrict__ perm, const int* __restrict__ offs,
    const float* __restrict__ top_w, int nmt, int nnt)
{
    constexpr int BK = 32;
    __shared__ __align__(16) short As[2][128 * 32];
    __shared__ __align__(16) short Bs[2][128 * 32];
    __shared__ int   rows_a[128];
    __shared__ int   rows_o[128];
    __shared__ float w_m[128];

    const int tid = threadIdx.x;

    // bijective XCD swizzle, mt innermost (blocks sharing a B-strip share L2)
    int wg = blockIdx.x;
    {
        const int nwg = gridDim.x;
        const int qq = nwg >> 3, rr = nwg & 7;
        const int xcd = wg & 7, lin = wg >> 3;
        wg = (xcd < rr ? xcd * (qq + 1) : rr * (qq + 1) + (xcd - rr) * qq) + lin;
    }
    const int mt = wg % nmt;
    const int nt = (wg / nmt) % nnt;
    const int e  = wg / (nmt * nnt);

    int off = 0, cnt = T_NUM;
    const short* Bt = Bg;
    if constexpr (MODE == 0 || MODE == 2) {
        off = offs[e]; cnt = offs[e + 1] - off;
        if (mt * 128 >= cnt) return;
        Bt = Bg + (size_t)e * ((size_t)nnt * 128) * Kdim;
    }

    if (tid < 128) {
        const int gm = mt * 128 + tid;
        if constexpr (MODE == 0) {
            int s = perm[off + (gm < cnt ? gm : cnt - 1)];
            rows_a[tid] = s >> 2; rows_o[tid] = s; w_m[tid] = 1.f;
        } else if constexpr (MODE == 2) {
            int s = perm[off + (gm < cnt ? gm : cnt - 1)];
            rows_a[tid] = s; rows_o[tid] = s >> 2; w_m[tid] = top_w[s];
        } else {
            rows_a[tid] = gm; rows_o[tid] = gm; w_m[tid] = 1.f;
        }
    }
    __syncthreads();

    // cache gathered A-row indices in registers (2 chunk-rows per thread)
    int raReg[2];
    #pragma unroll
    for (int it = 0; it < 2; ++it) raReg[it] = rows_a[it * 64 + (tid >> 2)];

    auto stage = [&](int buf, int kt) {
        const int k0 = kt * BK;
        #pragma unroll
        for (int it = 0; it < 2; ++it) {
            const int q = it * 256 + tid;
            const int m = q >> 2;
            const int c = ((q & 3) ^ ((m >> 1) & 3)) * 8;   // pre-swizzled source chunk
            gll16(A + (size_t)raReg[it] * lda + k0 + c, &As[buf][q * 8]);
        }
        #pragma unroll
        for (int it = 0; it < 2; ++it) {
            const int q = it * 256 + tid;
            const int n = q >> 2;
            const int c = ((q & 3) ^ ((n >> 1) & 3)) * 8;
            gll16(Bt + (size_t)(nt * 128 + n) * Kdim + k0 + c, &Bs[buf][q * 8]);
        }
    };

    f32x4 acc[4][4];
    #pragma unroll
    for (int i = 0; i < 4; ++i)
        #pragma unroll
        for (int j = 0; j < 4; ++j) acc[i][j] = (f32x4)0.f;

    const int lane = tid & 63;
    const int wr = (tid >> 7), wc = (tid >> 6) & 1;
    const int lrow = lane & 15;
    const int cswz = (((lane >> 4) ^ ((lrow >> 1) & 3)) * 8);  // same XOR on read side

    auto compute = [&](int buf) {
        bf16x8 af[4];
        #pragma unroll
        for (int mi = 0; mi < 4; ++mi)
            af[mi] = *reinterpret_cast<const bf16x8*>(&As[buf][(wr * 64 + mi * 16 + lrow) * 32 + cswz]);
        #pragma unroll
        for (int ni = 0; ni < 4; ++ni) {
            bf16x8 bfr = *reinterpret_cast<const bf16x8*>(&Bs[buf][(wc * 64 + ni * 16 + lrow) * 32 + cswz]);
            #pragma unroll
            for (int mi = 0; mi < 4; ++mi)
                acc[mi][ni] = __builtin_amdgcn_mfma_f32_16x16x32_bf16(af[mi], bfr, acc[mi][ni], 0, 0, 0);
        }
    };

    const int NK = Kdim / BK;
    stage(0, 0);
    int buf = 0;
    for (int kt = 0; kt < NK; ++kt) {
        if (kt + 1 < NK) {
            stage(buf ^ 1, kt + 1);
            asm volatile("s_waitcnt vmcnt(4)" ::: "memory");  // current buf's 4 loads done
        } else {
            asm volatile("s_waitcnt vmcnt(0)" ::: "memory");
        }
        __builtin_amdgcn_s_barrier();
        compute(buf);
        __builtin_amdgcn_s_barrier();   // all waves done reading buf before it's restaged
        buf ^= 1;
    }

    // epilogue
    #pragma unroll
    for (int mi = 0; mi < 4; ++mi) {
        #pragma unroll
        for (int j = 0; j < 4; ++j) {
            const int ml = wr * 64 + mi * 16 + (lane >> 4) * 4 + j;
            const int gm = mt * 128 + ml;
            if constexpr (MODE == 0 || MODE == 2) { if (gm >= cnt) continue; }
            const int orow = (MODE == 0 || MODE == 2) ? rows_o[ml] : gm;
            const float wsc = w_m[ml];
            #pragma unroll
            for (int ni = 0; ni < 4; ++ni) {
                const int n = nt * 128 + wc * 64 + ni * 16 + (lane & 15);
                const float v = acc[mi][ni][j];
                if constexpr (MODE == 0 || MODE == 1) {
                    ((short*)Outv)[(size_t)orow * ldo + n] = f2bf(v);
                } else if constexpr (MODE == 2) {
                    atomicAdd(&((float*)Outv)[(size_t)orow * ldo + n], v * wsc);
                } else {
                    ((float*)Outv)[(size_t)orow * ldo + n] = v;
                }
            }
        }
    }
}

// ================= FALLBACK (round-1 proven kernel, f32 weights inline) ========
template<int MODE>
__global__ __launch_bounds__(256, 2) void moe_gemm_fb(
    const float* __restrict__ A, int lda, int Kdim,
    const float* __restrict__ B1g, const float* __restrict__ B2g, int ldb,
    float* __restrict__ Out, int ldo,
    const int* __restrict__ perm, const int* __restrict__ offs,
    const float* __restrict__ top_w)
{
    constexpr int NB = (MODE == 0 || MODE == 1) ? 2 : 1;
    constexpr int BM = 128, BN = 128, BK = 32, KP = 40;
    __shared__ short As[2][BM * KP];
    __shared__ short Bs[2][NB * BN * KP];
    __shared__ int   rows_a[BM];
    __shared__ int   rows_o[BM];
    __shared__ float w_m[BM];

    const int tid = threadIdx.x;
    const int nt = blockIdx.x, mt = blockIdx.y, e = blockIdx.z;

    int off = 0, cnt = T_NUM;
    const float* B1 = B1g;
    const float* B2 = B2g;
    if constexpr (MODE == 0) {
        off = offs[e]; cnt = offs[e + 1] - off;
        if (mt * BM >= cnt) return;
        B1 = B1g + (size_t)e * H_DIM * I_DIM;
        B2 = B2g + (size_t)e * H_DIM * I_DIM;
    }
    if constexpr (MODE == 2) {
        off = offs[e]; cnt = offs[e + 1] - off;
        if (mt * BM >= cnt) return;
        B1 = B1g + (size_t)e * I_DIM * H_DIM;
    }

    if (tid < BM) {
        const int gm = mt * BM + tid;
        if constexpr (MODE == 0) {
            int s = perm[off + (gm < cnt ? gm : cnt - 1)];
            rows_a[tid] = s >> 2; rows_o[tid] = s; w_m[tid] = 1.f;
        } else if constexpr (MODE == 2) {
            int s = perm[off + (gm < cnt ? gm : cnt - 1)];
            rows_a[tid] = s; rows_o[tid] = s >> 2; w_m[tid] = top_w[s];
        } else {
            rows_a[tid] = gm; rows_o[tid] = gm; w_m[tid] = 1.f;
        }
    }
    __syncthreads();

    f32x4 aReg[4];
    float bReg[NB][4][4];

    auto gload = [&](int kt) {
        const int k0 = kt * BK;
        #pragma unroll
        for (int it = 0; it < 4; ++it) {
            const int q = it * 256 + tid;
            const int m = q >> 3, kq = (q & 7) * 4;
            aReg[it] = *reinterpret_cast<const f32x4*>(A + (size_t)rows_a[m] * lda + k0 + kq);
        }
        #pragma unroll
        for (int it = 0; it < 4; ++it) {
            const int q = it * 256 + tid;
            const int n = q & 127, kb = (q >> 7) * 4;
            const float* p1 = B1 + (size_t)(k0 + kb) * ldb + (size_t)nt * BN + n;
            #pragma unroll
            for (int dk = 0; dk < 4; ++dk) bReg[0][it][dk] = p1[(size_t)dk * ldb];
            if constexpr (NB == 2) {
                const float* p2 = B2 + (size_t)(k0 + kb) * ldb + (size_t)nt * BN + n;
                #pragma unroll
                for (int dk = 0; dk < 4; ++dk) bReg[1][it][dk] = p2[(size_t)dk * ldb];
            }
        }
    };

    auto swrite = [&](int buf) {
        #pragma unroll
        for (int it = 0; it < 4; ++it) {
            const int q = it * 256 + tid;
            const int m = q >> 3, kq = (q & 7) * 4;
            s16x4 v = { f2bf(aReg[it][0]), f2bf(aReg[it][1]), f2bf(aReg[it][2]), f2bf(aReg[it][3]) };
            *reinterpret_cast<s16x4*>(&As[buf][m * KP + kq]) = v;
        }
        #pragma unroll
        for (int it = 0; it < 4; ++it) {
            const int q = it * 256 + tid;
            const int n = q & 127, kb = (q >> 7) * 4;
            #pragma unroll
            for (int mat = 0; mat < NB; ++mat) {
                s16x4 v = { f2bf(bReg[mat][it][0]), f2bf(bReg[mat][it][1]),
                            f2bf(bReg[mat][it][2]), f2bf(bReg[mat][it][3]) };
                *reinterpret_cast<s16x4*>(&Bs[buf][mat * BN * KP + n * KP + kb]) = v;
            }
        }
    };

    f32x4 acc1[4][4], acc2[4][4];
    #pragma unroll
    for (int i = 0; i < 4; ++i)
        #pragma unroll
        for (int j = 0; j < 4; ++j) { acc1[i][j] = (f32x4)0.f; acc2[i][j] = (f32x4)0.f; }

    const int lane = tid & 63;
    const int wr = (tid >> 6) >> 1, wc = (tid >> 6) & 1;
    const int lrow = lane & 15;
    const int lko = (lane >> 4) * 8;

    auto compute = [&](int buf) {
        bf16x8 af[4];
        #pragma unroll
        for (int mi = 0; mi < 4; ++mi)
            af[mi] = *reinterpret_cast<const bf16x8*>(&As[buf][(wr * 64 + mi * 16 + lrow) * KP + lko]);
        #pragma unroll
        for (int ni = 0; ni < 4; ++ni) {
            const int brow = (wc * 64 + ni * 16 + lrow) * KP + lko;
            bf16x8 b1 = *reinterpret_cast<const bf16x8*>(&Bs[buf][brow]);
            #pragma unroll
            for (int mi = 0; mi < 4; ++mi)
                acc1[mi][ni] = __builtin_amdgcn_mfma_f32_16x16x32_bf16(af[mi], b1, acc1[mi][ni], 0, 0, 0);
            if constexpr (NB == 2) {
                bf16x8 b2 = *reinterpret_cast<const bf16x8*>(&Bs[buf][BN * KP + brow]);
                #pragma unroll
                for (int mi = 0; mi < 4; ++mi)
                    acc2[mi][ni] = __builtin_amdgcn_mfma_f32_16x16x32_bf16(af[mi], b2, acc2[mi][ni], 0, 0, 0);
            }
        }
    };

    const int NK = Kdim / BK;
    gload(0);
    int cur = 0;
    for (int kt = 0; kt < NK; ++kt) {
        swrite(cur);
        __syncthreads();
        if (kt + 1 < NK) gload(kt + 1);
        compute(cur);
        cur ^= 1;
        __syncthreads();
    }

    #pragma unroll
    for (int mi = 0; mi < 4; ++mi) {
        #pragma unroll
        for (int j = 0; j < 4; ++j) {
            const int ml = wr * 64 + mi * 16 + (lane >> 4) * 4 + j;
            const int gm = mt * BM + ml;
            if constexpr (MODE == 0 || MODE == 2) { if (gm >= cnt) continue; }
            const int orow = rows_o[ml];
            const float wsc = w_m[ml];
            #pragma unroll
            for (int ni = 0; ni < 4; ++ni) {
                const int n = nt * BN + wc * 64 + ni * 16 + (lane & 15);
                const float v1 = acc1[mi][ni][j];
                if constexpr (NB == 2) {
                    const float u = acc2[mi][ni][j];
                    const float s = v1 / (1.f + __expf(-v1));
                    Out[(size_t)orow * ldo + n] = s * u;
                } else if constexpr (MODE == 2) {
                    atomicAdd(&Out[(size_t)orow * ldo + n], v1 * wsc);
                } else {
                    Out[(size_t)orow * ldo + n] = v1;
                }
            }
        }
    }
}

extern "C" void kernel_launch(void* const* d_in, const int* in_sizes, int n_in,
                              void* d_out, int out_size, void* d_ws, size_t ws_size,
                              hipStream_t stream) {
    const float* x     = (const float*)d_in[0];
    const float* wgate = (const float*)d_in[1];
    const float* wg    = (const float*)d_in[2];
    const float* wu    = (const float*)d_in[3];
    const float* wd    = (const float*)d_in[4];
    const float* sg    = (const float*)d_in[5];
    const float* su    = (const float*)d_in[6];
    const float* sd    = (const float*)d_in[7];
    float* out = (float*)d_out;

    uintptr_t p0 = (uintptr_t)d_ws;
    uintptr_t p = p0;
    auto alloc = [&](size_t bytes) {
        p = (p + 255) & ~(uintptr_t)255;
        void* r = (void*)p; p += bytes; return r;
    };
    int*   top_e = (int*)alloc((size_t)T_NUM * TOPK * sizeof(int));
    float* top_w = (float*)alloc((size_t)T_NUM * TOPK * sizeof(float));
    int*   offs  = (int*)alloc((E_NUM + 1) * sizeof(int));
    int*   perm  = (int*)alloc((size_t)T_NUM * TOPK * sizeof(int));
    short* xb    = (short*)alloc((size_t)T_NUM * H_DIM * 2);

    const size_t wguSz = (size_t)E_NUM * H_DIM * I_DIM * 2;   // 92.3 MB each
    const size_t shSz  = (size_t)H_DIM * SHI_DIM * 2;          // 11.5 MB each

    // primary-path workspace requirement
    const size_t need = ((size_t)T_NUM * TOPK * 8 + 4096) + (size_t)T_NUM * H_DIM * 2
                      + 3 * wguSz + 3 * shSz
                      + 3 * (size_t)T_NUM * TOPK * I_DIM * 2
                      + 3 * (size_t)T_NUM * SHI_DIM * 2
                      + (1u << 20);

    router_kernel<<<T_NUM, 256, 0, stream>>>(x, wgate, top_e, top_w, xb);
    perm_kernel<<<1, 256, 0, stream>>>(top_e, offs, perm);

    if (ws_size >= need) {
        short* wgT = (short*)alloc(wguSz);   // [e][I][H]
        short* wuT = (short*)alloc(wguSz);   // [e][I][H]
        short* wdT = (short*)alloc(wguSz);   // [e][H][I]
        short* sgT = (short*)alloc(shSz);    // [SHI][H]
        short* suT = (short*)alloc(shSz);    // [SHI][H]
        short* sdT = (short*)alloc(shSz);    // [H][SHI]
        short* g_r = (short*)alloc((size_t)T_NUM * TOPK * I_DIM * 2);
        short* u_r = (short*)alloc((size_t)T_NUM * TOPK * I_DIM * 2);
        short* act_r = (short*)alloc((size_t)T_NUM * TOPK * I_DIM * 2);
        short* g_s = (short*)alloc((size_t)T_NUM * SHI_DIM * 2);
        short* u_s = (short*)alloc((size_t)T_NUM * SHI_DIM * 2);
        short* act_s = (short*)alloc((size_t)T_NUM * SHI_DIM * 2);

        // weight transpose+convert: f32 [R][C] -> bf16 [C][R]
        tconv_kernel<<<dim3(I_DIM / 64, H_DIM / 64, E_NUM), 256, 0, stream>>>(wg, wgT, H_DIM, I_DIM);
        tconv_kernel<<<dim3(I_DIM / 64, H_DIM / 64, E_NUM), 256, 0, stream>>>(wu, wuT, H_DIM, I_DIM);
        tconv_kernel<<<dim3(H_DIM / 64, I_DIM / 64, E_NUM), 256, 0, stream>>>(wd, wdT, I_DIM, H_DIM);
        tconv_kernel<<<dim3(SHI_DIM / 64, H_DIM / 64, 1), 256, 0, stream>>>(sg, sgT, H_DIM, SHI_DIM);
        tconv_kernel<<<dim3(SHI_DIM / 64, H_DIM / 64, 1), 256, 0, stream>>>(su, suT, H_DIM, SHI_DIM);
        tconv_kernel<<<dim3(H_DIM / 64, SHI_DIM / 64, 1), 256, 0, stream>>>(sd, sdT, SHI_DIM, H_DIM);

        const int nmtT = T_NUM / 128;            // 8
        const int nnI = I_DIM / 128;             // 11
        const int nnH = H_DIM / 128;             // 16
        const int nnS = SHI_DIM / 128;           // 22

        // shared chain
        gemm_bf<1><<<nmtT * nnS, 256, 0, stream>>>(xb, H_DIM, H_DIM, sgT, g_s, SHI_DIM,
                                                   nullptr, nullptr, nullptr, nmtT, nnS);
        gemm_bf<1><<<nmtT * nnS, 256, 0, stream>>>(xb, H_DIM, H_DIM, suT, u_s, SHI_DIM,
                                                   nullptr, nullptr, nullptr, nmtT, nnS);
        swiglu_kernel<<<(T_NUM * SHI_DIM / 8 + 255) / 256, 256, 0, stream>>>(
            g_s, u_s, act_s, T_NUM * SHI_DIM / 8);
        gemm_bf<3><<<nmtT * nnH, 256, 0, stream>>>(act_s, SHI_DIM, SHI_DIM, sdT, out, H_DIM,
                                                   nullptr, nullptr, nullptr, nmtT, nnH);
        // routed chain
        gemm_bf<0><<<nmtT * nnI * E_NUM, 256, 0, stream>>>(xb, H_DIM, H_DIM, wgT, g_r, I_DIM,
                                                           perm, offs, nullptr, nmtT, nnI);
        gemm_bf<0><<<nmtT * nnI * E_NUM, 256, 0, stream>>>(xb, H_DIM, H_DIM, wuT, u_r, I_DIM,
                                                           perm, offs, nullptr, nmtT, nnI);
        swiglu_kernel<<<(T_NUM * TOPK * I_DIM / 8 + 255) / 256, 256, 0, stream>>>(
            g_r, u_r, act_r, T_NUM * TOPK * I_DIM / 8);
        gemm_bf<2><<<nmtT * nnH * E_NUM, 256, 0, stream>>>(act_r, I_DIM, I_DIM, wdT, out, H_DIM,
                                                           perm, offs, top_w, nmtT, nnH);
    } else {
        // fallback: round-1 proven path (f32 weights inline, f32 acts)
        float* act_r = (float*)alloc((size_t)T_NUM * TOPK * I_DIM * sizeof(float));
        float* act_s = (float*)alloc((size_t)T_NUM * SHI_DIM * sizeof(float));

        moe_gemm_fb<1><<<dim3(SHI_DIM / 128, T_NUM / 128, 1), 256, 0, stream>>>(
            x, H_DIM, H_DIM, sg, su, SHI_DIM, act_s, SHI_DIM, nullptr, nullptr, nullptr);
        moe_gemm_fb<3><<<dim3(H_DIM / 128, T_NUM / 128, 1), 256, 0, stream>>>(
            act_s, SHI_DIM, SHI_DIM, sd, nullptr, H_DIM, out, H_DIM, nullptr, nullptr, nullptr);
        moe_gemm_fb<0><<<dim3(I_DIM / 128, T_NUM / 128, E_NUM), 256, 0, stream>>>(
            x, H_DIM, H_DIM, wg, wu, I_DIM, act_r, I_DIM, perm, offs, nullptr);
        moe_gemm_fb<2><<<dim3(H_DIM / 128, T_NUM / 128, E_NUM), 256, 0, stream>>>(
            act_r, I_DIM, I_DIM, wd, nullptr, H_DIM, out, H_DIM, perm, offs, top_w);
    }
}